// Round 15
// baseline (82.329 us; speedup 1.0000x reference)
//
#include <hip/hip_runtime.h>
#include <hip/hip_bf16.h>
#include <stdint.h>

#define NTOK 4096
#define DIM  256
#define HID  1024
#define NEXP 8
#define MTILE 64
#define HC 32
#define HSLICE 256
#define NSLICE 4
#define NCHUNK (HSLICE / HC)   // 8

typedef float f32x4 __attribute__((ext_vector_type(4)));
typedef short s16x8 __attribute__((ext_vector_type(8)));

__device__ __forceinline__ unsigned short f2bf(float f) {
  union { float f; unsigned u; } v; v.f = f;
  unsigned r = v.u + 0x7FFFu + ((v.u >> 16) & 1u);
  return (unsigned short)(r >> 16);
}
__device__ __forceinline__ float bf2f(unsigned short s) {
  union { float f; unsigned u; } v; v.u = ((unsigned)s) << 16;
  return v.f;
}
__device__ __forceinline__ void mfma16(f32x4& acc, s16x8 a, s16x8 b) {
  asm("v_mfma_f32_16x16x32_bf16 %0, %1, %2, %0" : "+v"(acc) : "v"(a), "v"(b));
}
__device__ __forceinline__ void accfence(f32x4& a) {   // MFMA->VALU read hazard
  asm volatile("s_nop 7" : "+v"(a));
}
__device__ __forceinline__ void initfence(f32x4& a) {  // VALU init -> MFMA srcC hazard
  asm volatile("s_nop 1" : "+v"(a));
}

// ---- merged prep (W1/W2 transpose+bf16+swizzle) + gate/route, one kernel ----
// blocks [0,2048): W1 -> W1T [E][1024][256] bf16, col' = col ^ ((row&7)<<3)
// blocks [2048,4096): W2 -> W2T chunk-tiled [E][H/32][D][32] bf16 (16 KB/chunk),
//   slot' = slot ^ ((d>>1)&3) within each 32-elem d-row
// blocks [4096,4352): gate+top2+routing, 16 tokens/block
__global__ __launch_bounds__(256) void prep_gate(
    const float* __restrict__ W1, const float* __restrict__ W2,
    unsigned short* __restrict__ W1T, unsigned short* __restrict__ W2T,
    const float* __restrict__ x, const float* __restrict__ gW,
    const float* __restrict__ gb, const float* __restrict__ temp,
    int* __restrict__ counts, int* __restrict__ list,
    unsigned short* __restrict__ xbf) {
  int id = blockIdx.x;
  int tx = threadIdx.x, ty = threadIdx.y;

  if (id < 4096) {   // ---------- transpose jobs ----------
    __shared__ float tile[32][33];
    const float* in; unsigned short* out; int R, C, bx, by, e, sw;
    if (id < 2048) {
      e = id >> 8; int rem = id & 255; by = rem >> 5; bx = rem & 31;
      in = W1; out = W1T; R = 256; C = 1024; sw = 1;
    } else {
      int id2 = id - 2048;
      e = id2 >> 8; int rem = id2 & 255; by = (rem >> 3) & 31; bx = rem & 7;
      in = W2; out = W2T; R = 1024; C = 256; sw = 0;
    }
    int r0 = by * 32, c0 = bx * 32;
    const float* ip = in + (size_t)e * R * C;
    unsigned short* op = out + (size_t)e * R * C;
    #pragma unroll
    for (int k = 0; k < 4; ++k)
      tile[ty + 8*k][tx] = ip[(size_t)(r0 + ty + 8*k) * C + c0 + tx];
    __syncthreads();
    #pragma unroll
    for (int k = 0; k < 4; ++k) {
      float v = tile[tx][ty + 8*k];
      if (sw) {
        int row = c0 + ty + 8*k;
        int col = r0 + tx;
        op[(size_t)row * R + (col ^ ((row & 7) << 3))] = f2bf(v);
      } else {
        int d = c0 + ty + 8*k;
        int h = r0 + tx;
        int ch = h >> 5, kk = h & 31;
        int slot = (kk >> 3) ^ ((d >> 1) & 3);
        op[(size_t)ch * (DIM * 32) + d * 32 + slot * 8 + (kk & 7)] = f2bf(v);
      }
    }
    return;
  }

  // ---------- gate job (16 tokens/block) ----------
  __shared__ int pairs[16][2];
  __shared__ int lcnt[NEXP], lbase[NEXP], lrank[NEXP];
  int tid = ty * 32 + tx;
  int w = tid >> 6, lane = tid & 63;
  int sl = lane & 15, g = lane >> 4;
  if (tid < NEXP) { lcnt[tid] = 0; lrank[tid] = 0; }
  __syncthreads();
  int t0 = (id - 4096) * 16;
  int tok = w * 4 + g;
  int n = t0 + tok;

  float4 xv[4];
  #pragma unroll
  for (int p = 0; p < 4; ++p)
    xv[p] = *reinterpret_cast<const float4*>(x + (size_t)n * DIM + sl * 16 + p * 4);
  {
    s16x8 xb0, xb1;
    xb0[0]=(short)f2bf(xv[0].x); xb0[1]=(short)f2bf(xv[0].y); xb0[2]=(short)f2bf(xv[0].z); xb0[3]=(short)f2bf(xv[0].w);
    xb0[4]=(short)f2bf(xv[1].x); xb0[5]=(short)f2bf(xv[1].y); xb0[6]=(short)f2bf(xv[1].z); xb0[7]=(short)f2bf(xv[1].w);
    xb1[0]=(short)f2bf(xv[2].x); xb1[1]=(short)f2bf(xv[2].y); xb1[2]=(short)f2bf(xv[2].z); xb1[3]=(short)f2bf(xv[2].w);
    xb1[4]=(short)f2bf(xv[3].x); xb1[5]=(short)f2bf(xv[3].y); xb1[6]=(short)f2bf(xv[3].z); xb1[7]=(short)f2bf(xv[3].w);
    *reinterpret_cast<s16x8*>(xbf + (size_t)n * DIM + sl * 16)     = xb0;
    *reinterpret_cast<s16x8*>(xbf + (size_t)n * DIM + sl * 16 + 8) = xb1;
  }
  float acc[NEXP];
  #pragma unroll
  for (int e = 0; e < NEXP; ++e) {
    const float* we = gW + (size_t)e * DIM + sl * 16;
    float a = 0.f;
    #pragma unroll
    for (int p = 0; p < 4; ++p) {
      float4 wv = *reinterpret_cast<const float4*>(we + p * 4);
      a += xv[p].x*wv.x + xv[p].y*wv.y + xv[p].z*wv.z + xv[p].w*wv.w;
    }
    acc[e] = a;
  }
  #pragma unroll
  for (int off = 1; off < 16; off <<= 1) {
    #pragma unroll
    for (int e = 0; e < NEXP; ++e) acc[e] += __shfl_xor(acc[e], off);
  }
  if (sl == 0) {
    float t = temp[0];
    float s[NEXP];
    #pragma unroll
    for (int e = 0; e < NEXP; ++e) s[e] = (acc[e] + gb[e]) / t;
    int b0 = 0; float v0 = s[0];
    #pragma unroll
    for (int e = 1; e < NEXP; ++e) if (s[e] > v0) { v0 = s[e]; b0 = e; }
    int b1i = 0; float v1 = -3.4e38f;
    #pragma unroll
    for (int e = 0; e < NEXP; ++e) if (e != b0 && s[e] > v1) { v1 = s[e]; b1i = e; }
    pairs[tok][0] = b0;
    pairs[tok][1] = b1i;
    atomicAdd(&lcnt[b0], 1);
    atomicAdd(&lcnt[b1i], 1);
  }
  __syncthreads();
  if (tid < NEXP) lbase[tid] = atomicAdd(&counts[tid], lcnt[tid]);
  __syncthreads();
  if (tid < 32) {
    int tk = tid >> 1;
    int e = pairs[tk][tid & 1];
    int r = atomicAdd(&lrank[e], 1);
    list[e * NTOK + lbase[e] + r] = (t0 + tk) * 2 + (tid & 1);
  }
}

// ---- fused FFN (r12 config + setprio + exact-512 grid with tile loop) ----
// 256 thr / 4 waves, MTILE=64, HC=32, NSLICE=4; LDS 74 KB -> 2 blocks/CU.
// iter c: [lgkm;bar] stage{W1(c+1),W2(c)} vmcnt(8) setprio(1){GEMM1(c)||GEMM2(c-1)}setprio(0) h->hs[c&1]
__global__ __launch_bounds__(256, 2) void moe_ffn(
    const unsigned short* __restrict__ xbf,
    const unsigned short* __restrict__ W1T,  // [E][H][D] bf16, swizzled
    const unsigned short* __restrict__ W2T,  // [E][H/32][D][32] bf16, chunk-tiled
    const float* __restrict__ b1g, const float* __restrict__ b2g,
    const int* __restrict__ counts, const int* __restrict__ list,
    unsigned short* __restrict__ ybuf) {
  int b = blockIdx.x;
  int e = b & 7;
  int r = b >> 3;
  int s = r & (NSLICE - 1);
  int t = r >> 2;          // 0..15
  int cnt = counts[e];
  if (t * MTILE >= cnt) return;

  __shared__ __align__(16) short W1b[2][HC * 256];   // 32 KB
  __shared__ __align__(16) short W2b[2][256 * HC];   // 32 KB
  __shared__ __align__(16) short hs[2][64][40];      // 10 KB

  int tid = threadIdx.x;
  int l = tid & 63, w = tid >> 6;
  int lr = l & 15, lg = l >> 4, kg = lg * 8;
  int wm = w & 1, wn = w >> 1;   // wm: 32-tok half; wn: hcol16 (GEMM1) / d-half128 (GEMM2)
  int hbase = s * HSLICE;
  const unsigned short* W1e = W1T + (size_t)e * HID * DIM;
  const unsigned short* W2e = W2T + (size_t)e * HID * DIM;

  auto stage1 = [&](int hc, int buf) {   // W1 chunk: 16 KB linear, 4 loads/wave
    const char* src = (const char*)(W1e + (size_t)hc * DIM);
    char* dst = (char*)&W1b[buf][0];
    #pragma unroll
    for (int i = 0; i < 4; ++i) {
      int off = w * 4096 + i * 1024;
      __builtin_amdgcn_global_load_lds(
        (const __attribute__((address_space(1))) void*)(src + off + l * 16),
        (__attribute__((address_space(3))) void*)(dst + off), 16, 0, 0);
    }
  };
  auto stage2 = [&](int hc, int buf) {   // W2 chunk: 16 KB linear, 4 loads/wave
    const char* src = (const char*)(W2e + (size_t)(hc >> 5) * (DIM * 32));
    char* dst = (char*)&W2b[buf][0];
    #pragma unroll
    for (int i = 0; i < 4; ++i) {
      int off = w * 4096 + i * 1024;
      __builtin_amdgcn_global_load_lds(
        (const __attribute__((address_space(1))) void*)(src + off + l * 16),
        (__attribute__((address_space(3))) void*)(dst + off), 16, 0, 0);
    }
  };

  float bbreg[NCHUNK];
  #pragma unroll
  for (int c = 0; c < NCHUNK; ++c)
    bbreg[c] = b1g[e * HID + hbase + c * HC + wn * 16 + lr];

  float b2v[8];
  #pragma unroll
  for (int n = 0; n < 8; ++n)
    b2v[n] = (s == 0) ? b2g[e * DIM + wn * 128 + n * 16 + lr] : 0.f;

  int swz = (lr & 7) << 3;
  int brow = (wn * 16 + lr) << 8;   // W1b row base (256 elems/row)

  bool first_tile = true;
  for (int tt = t; tt * MTILE < cnt; tt += 16) {
    const int* mylist = list + e * NTOK + tt * MTILE;

    if (first_tile) stage1(hbase, 0);   // later tiles: chunk0 pre-staged by wrap prefetch

    s16x8 xa[2][8];
    #pragma unroll
    for (int mf = 0; mf < 2; ++mf) {
      int row = wm * 32 + mf * 16 + lr;
      int grow = tt * MTILE + row;
      int entry = (grow < cnt) ? mylist[row] : mylist[0];
      const unsigned short* xsrc = xbf + (size_t)(entry >> 1) * DIM;
      #pragma unroll
      for (int kb = 0; kb < 8; ++kb)
        xa[mf][kb] = *(const s16x8*)(xsrc + kb * 32 + kg);
    }

    f32x4 acc[2][8] = {};
    #pragma unroll
    for (int mf = 0; mf < 2; ++mf) {
      #pragma unroll
      for (int n = 0; n < 8; ++n) initfence(acc[mf][n]);
    }

    if (first_tile) {
      __syncthreads();   // prologue drain once (stage1(0), bbreg, b2v, xa complete)
      first_tile = false;
    }

    #pragma unroll
    for (int c = 0; c < NCHUNK; ++c) {
      int P = c & 1, Q = P ^ 1;

      // single all-wave sync per chunk; loads stay in flight across it
      asm volatile("s_waitcnt lgkmcnt(0)" ::: "memory");
      __builtin_amdgcn_s_barrier();
      __builtin_amdgcn_sched_barrier(0);

      // stage next: W1(c+1)->W1b[Q] (wraps for next tile), W2(c)->W2b[P]
      stage1(hbase + (((c + 1) & (NCHUNK - 1)) * HC), Q);
      stage2(hbase + c * HC, P);

      // counted wait: previous iter's 8 loads must complete (never drains own)
      asm volatile("s_waitcnt vmcnt(8)" ::: "memory");
      __builtin_amdgcn_sched_barrier(0);

      __builtin_amdgcn_s_setprio(1);   // T5: favor MFMA-cluster waves

      // GEMM1(c): h(64x32) = X @ W1chunk^T ; A regs (2 tok-groups), B LDS shared
      f32x4 h0[2] = {}, h1[2] = {};
      initfence(h0[0]); initfence(h0[1]); initfence(h1[0]); initfence(h1[1]);
      const short* w1p = &W1b[P][0];
      #pragma unroll
      for (int kb = 0; kb < 8; ++kb) {
        s16x8 bv = *(const s16x8*)&w1p[brow + ((kb * 32 + kg) ^ swz)];
        if (kb & 1) { mfma16(h1[0], xa[0][kb], bv); mfma16(h1[1], xa[1][kb], bv); }
        else        { mfma16(h0[0], xa[0][kb], bv); mfma16(h0[1], xa[1][kb], bv); }
      }

      // GEMM2(c-1): y += h(c-1) @ W2(c-1)^T — independent, interleaves with GEMM1
      if (c > 0) {
        s16x8 a0 = *(const s16x8*)&hs[Q][wm * 32 + lr][kg];
        s16x8 a1 = *(const s16x8*)&hs[Q][wm * 32 + 16 + lr][kg];
        const short* w2p = &W2b[Q][0];
        #pragma unroll
        for (int n = 0; n < 8; ++n) {
          int d = wn * 128 + n * 16 + lr;
          s16x8 bv = *(const s16x8*)&w2p[(d << 5) + ((lg ^ ((d >> 1) & 3)) << 3)];
          mfma16(acc[0][n], a0, bv);
          mfma16(acc[1][n], a1, bv);
        }
      }

      __builtin_amdgcn_s_setprio(0);

      // finish h(c): +b1, relu, write hs[P] for next iter
      accfence(h0[0]); accfence(h0[1]); accfence(h1[0]); accfence(h1[1]);
      float bb = bbreg[c];
      #pragma unroll
      for (int mf = 0; mf < 2; ++mf) {
        f32x4 h = h0[mf] + h1[mf];
        #pragma unroll
        for (int q = 0; q < 4; ++q)
          hs[P][wm * 32 + mf * 16 + lg * 4 + q][wn * 16 + lr] = (short)f2bf(fmaxf(h[q] + bb, 0.f));
      }
    }

    // per-tile epilogue: GEMM2 for last chunk
    asm volatile("s_waitcnt vmcnt(0) lgkmcnt(0)" ::: "memory");
    __builtin_amdgcn_s_barrier();
    __builtin_amdgcn_sched_barrier(0);
    {
      const int Q = (NCHUNK - 1) & 1;   // = 1
      s16x8 a0 = *(const s16x8*)&hs[Q][wm * 32 + lr][kg];
      s16x8 a1 = *(const s16x8*)&hs[Q][wm * 32 + 16 + lr][kg];
      const short* w2p = &W2b[Q][0];
      #pragma unroll
      for (int n = 0; n < 8; ++n) {
        int d = wn * 128 + n * 16 + lr;
        s16x8 bv = *(const s16x8*)&w2p[(d << 5) + ((lg ^ ((d >> 1) & 3)) << 3)];
        mfma16(acc[0][n], a0, bv);
        mfma16(acc[1][n], a1, bv);
      }
    }

    // store bf16 partials to slot buffer (+b2 on slice 0)
    #pragma unroll
    for (int mf = 0; mf < 2; ++mf) {
      #pragma unroll
      for (int n = 0; n < 8; ++n) accfence(acc[mf][n]);
    }
    #pragma unroll
    for (int mf = 0; mf < 2; ++mf) {
      #pragma unroll
      for (int q = 0; q < 4; ++q) {
        int lrow = wm * 32 + mf * 16 + lg * 4 + q;
        int grow = tt * MTILE + lrow;
        if (grow < cnt) {
          int entry = mylist[lrow];
          unsigned short* yrow = ybuf + ((size_t)entry * NSLICE + s) * DIM + wn * 128 + lr;
          #pragma unroll
          for (int n = 0; n < 8; ++n)
            yrow[n * 16] = f2bf(acc[mf][n][q] + b2v[n]);
        }
      }
    }
  }
}

// ---- out[n][d] = sum of 8 slot-rows of bf16 ybuf ----
__global__ __launch_bounds__(256) void reduce8(const unsigned short* __restrict__ yb,
                                               float* __restrict__ out) {
  int i = (blockIdx.x * 256 + threadIdx.x) * 8;
  int n = i >> 8, d = i & 255;
  const unsigned short* base = yb + ((size_t)n * 8) * DIM + d;
  float sum[8] = {0,0,0,0,0,0,0,0};
  #pragma unroll
  for (int r = 0; r < 8; ++r) {
    s16x8 v = *(const s16x8*)(base + r * DIM);
    #pragma unroll
    for (int j = 0; j < 8; ++j) sum[j] += bf2f((unsigned short)v[j]);
  }
  float4 o0 = {sum[0], sum[1], sum[2], sum[3]};
  float4 o1 = {sum[4], sum[5], sum[6], sum[7]};
  *(float4*)(out + i) = o0;
  *(float4*)(out + i + 4) = o1;
}

extern "C" void kernel_launch(void* const* d_in, const int* in_sizes, int n_in,
                              void* d_out, int out_size, void* d_ws, size_t ws_size,
                              hipStream_t stream) {
  const float* x    = (const float*)d_in[0];
  const float* gW   = (const float*)d_in[1];
  const float* gb   = (const float*)d_in[2];
  const float* W1   = (const float*)d_in[3];
  const float* b1   = (const float*)d_in[4];
  const float* W2   = (const float*)d_in[5];
  const float* b2   = (const float*)d_in[6];
  const float* temp = (const float*)d_in[7];
  float* out = (float*)d_out;

  char* ws = (char*)d_ws;
  int*            counts = (int*)(ws + 0);                      // 256 B
  int*            list   = (int*)(ws + 256);                    // 128 KB
  unsigned short* xbf    = (unsigned short*)(ws + 131584);      // 2 MB
  unsigned short* W1T    = (unsigned short*)(ws + 2228736);     // 4 MB
  unsigned short* W2T    = (unsigned short*)(ws + 6423040);     // 4 MB
  unsigned short* ybuf   = (unsigned short*)(ws + 10617344);    // 16 MB bf16 (8 slots/token)

  hipMemsetAsync(counts, 0, 256, stream);
  prep_gate<<<4096 + NTOK/16, dim3(32, 8, 1), 0, stream>>>(
      W1, W2, W1T, W2T, x, gW, gb, temp, counts, list, xbf);
  moe_ffn<<<NEXP * 16 * NSLICE, 256, 0, stream>>>(xbf, W1T, W2T, b1, b2, counts, list, ybuf);
  reduce8<<<NTOK*DIM/2048, 256, 0, stream>>>(ybuf, out);
}

// Round 16
// 56.311 us; speedup vs baseline: 1.4620x; 1.4620x over previous
//
#include <hip/hip_runtime.h>
#include <hip/hip_bf16.h>
#include <stdint.h>

#define NTOK 4096
#define DIM  256
#define HID  1024
#define NEXP 8
#define MTILE 64
#define HC 32
#define HSLICE 256
#define NSLICE 4
#define NCHUNK (HSLICE / HC)   // 8

typedef float f32x4 __attribute__((ext_vector_type(4)));
typedef short s16x8 __attribute__((ext_vector_type(8)));

__device__ __forceinline__ unsigned short f2bf(float f) {
  union { float f; unsigned u; } v; v.f = f;
  unsigned r = v.u + 0x7FFFu + ((v.u >> 16) & 1u);
  return (unsigned short)(r >> 16);
}
__device__ __forceinline__ float bf2f(unsigned short s) {
  union { float f; unsigned u; } v; v.u = ((unsigned)s) << 16;
  return v.f;
}
__device__ __forceinline__ void mfma16(f32x4& acc, s16x8 a, s16x8 b) {
  asm("v_mfma_f32_16x16x32_bf16 %0, %1, %2, %0" : "+v"(acc) : "v"(a), "v"(b));
}
__device__ __forceinline__ void accfence(f32x4& a) {   // MFMA->VALU read hazard
  asm volatile("s_nop 7" : "+v"(a));
}
__device__ __forceinline__ void initfence(f32x4& a) {  // VALU init -> MFMA srcC hazard
  asm volatile("s_nop 1" : "+v"(a));
}

// ---- merged prep (W1/W2 transpose+bf16+swizzle) + gate/route, one kernel ----
// blocks [0,2048): W1 -> W1T [E][1024][256] bf16, col' = col ^ ((row&7)<<3)
// blocks [2048,4096): W2 -> W2T chunk-tiled [E][H/32][D][32] bf16 (16 KB/chunk),
//   slot' = slot ^ ((d>>1)&3) within each 32-elem d-row
// blocks [4096,4352): gate+top2+routing, 16 tokens/block
__global__ __launch_bounds__(256) void prep_gate(
    const float* __restrict__ W1, const float* __restrict__ W2,
    unsigned short* __restrict__ W1T, unsigned short* __restrict__ W2T,
    const float* __restrict__ x, const float* __restrict__ gW,
    const float* __restrict__ gb, const float* __restrict__ temp,
    int* __restrict__ counts, int* __restrict__ list,
    unsigned short* __restrict__ xbf) {
  int id = blockIdx.x;
  int tx = threadIdx.x, ty = threadIdx.y;

  if (id < 4096) {   // ---------- transpose jobs ----------
    __shared__ float tile[32][33];
    const float* in; unsigned short* out; int R, C, bx, by, e, sw;
    if (id < 2048) {
      e = id >> 8; int rem = id & 255; by = rem >> 5; bx = rem & 31;
      in = W1; out = W1T; R = 256; C = 1024; sw = 1;
    } else {
      int id2 = id - 2048;
      e = id2 >> 8; int rem = id2 & 255; by = (rem >> 3) & 31; bx = rem & 7;
      in = W2; out = W2T; R = 1024; C = 256; sw = 0;
    }
    int r0 = by * 32, c0 = bx * 32;
    const float* ip = in + (size_t)e * R * C;
    unsigned short* op = out + (size_t)e * R * C;
    #pragma unroll
    for (int k = 0; k < 4; ++k)
      tile[ty + 8*k][tx] = ip[(size_t)(r0 + ty + 8*k) * C + c0 + tx];
    __syncthreads();
    #pragma unroll
    for (int k = 0; k < 4; ++k) {
      float v = tile[tx][ty + 8*k];
      if (sw) {
        int row = c0 + ty + 8*k;
        int col = r0 + tx;
        op[(size_t)row * R + (col ^ ((row & 7) << 3))] = f2bf(v);
      } else {
        int d = c0 + ty + 8*k;
        int h = r0 + tx;
        int ch = h >> 5, kk = h & 31;
        int slot = (kk >> 3) ^ ((d >> 1) & 3);
        op[(size_t)ch * (DIM * 32) + d * 32 + slot * 8 + (kk & 7)] = f2bf(v);
      }
    }
    return;
  }

  // ---------- gate job (16 tokens/block) ----------
  __shared__ int pairs[16][2];
  __shared__ int lcnt[NEXP], lbase[NEXP], lrank[NEXP];
  int tid = ty * 32 + tx;
  int w = tid >> 6, lane = tid & 63;
  int sl = lane & 15, g = lane >> 4;
  if (tid < NEXP) { lcnt[tid] = 0; lrank[tid] = 0; }
  __syncthreads();
  int t0 = (id - 4096) * 16;
  int tok = w * 4 + g;
  int n = t0 + tok;

  float4 xv[4];
  #pragma unroll
  for (int p = 0; p < 4; ++p)
    xv[p] = *reinterpret_cast<const float4*>(x + (size_t)n * DIM + sl * 16 + p * 4);
  {
    s16x8 xb0, xb1;
    xb0[0]=(short)f2bf(xv[0].x); xb0[1]=(short)f2bf(xv[0].y); xb0[2]=(short)f2bf(xv[0].z); xb0[3]=(short)f2bf(xv[0].w);
    xb0[4]=(short)f2bf(xv[1].x); xb0[5]=(short)f2bf(xv[1].y); xb0[6]=(short)f2bf(xv[1].z); xb0[7]=(short)f2bf(xv[1].w);
    xb1[0]=(short)f2bf(xv[2].x); xb1[1]=(short)f2bf(xv[2].y); xb1[2]=(short)f2bf(xv[2].z); xb1[3]=(short)f2bf(xv[2].w);
    xb1[4]=(short)f2bf(xv[3].x); xb1[5]=(short)f2bf(xv[3].y); xb1[6]=(short)f2bf(xv[3].z); xb1[7]=(short)f2bf(xv[3].w);
    *reinterpret_cast<s16x8*>(xbf + (size_t)n * DIM + sl * 16)     = xb0;
    *reinterpret_cast<s16x8*>(xbf + (size_t)n * DIM + sl * 16 + 8) = xb1;
  }
  float acc[NEXP];
  #pragma unroll
  for (int e = 0; e < NEXP; ++e) {
    const float* we = gW + (size_t)e * DIM + sl * 16;
    float a = 0.f;
    #pragma unroll
    for (int p = 0; p < 4; ++p) {
      float4 wv = *reinterpret_cast<const float4*>(we + p * 4);
      a += xv[p].x*wv.x + xv[p].y*wv.y + xv[p].z*wv.z + xv[p].w*wv.w;
    }
    acc[e] = a;
  }
  #pragma unroll
  for (int off = 1; off < 16; off <<= 1) {
    #pragma unroll
    for (int e = 0; e < NEXP; ++e) acc[e] += __shfl_xor(acc[e], off);
  }
  if (sl == 0) {
    float t = temp[0];
    float s[NEXP];
    #pragma unroll
    for (int e = 0; e < NEXP; ++e) s[e] = (acc[e] + gb[e]) / t;
    int b0 = 0; float v0 = s[0];
    #pragma unroll
    for (int e = 1; e < NEXP; ++e) if (s[e] > v0) { v0 = s[e]; b0 = e; }
    int b1i = 0; float v1 = -3.4e38f;
    #pragma unroll
    for (int e = 0; e < NEXP; ++e) if (e != b0 && s[e] > v1) { v1 = s[e]; b1i = e; }
    pairs[tok][0] = b0;
    pairs[tok][1] = b1i;
    atomicAdd(&lcnt[b0], 1);
    atomicAdd(&lcnt[b1i], 1);
  }
  __syncthreads();
  if (tid < NEXP) lbase[tid] = atomicAdd(&counts[tid], lcnt[tid]);
  __syncthreads();
  if (tid < 32) {
    int tk = tid >> 1;
    int e = pairs[tk][tid & 1];
    int r = atomicAdd(&lrank[e], 1);
    list[e * NTOK + lbase[e] + r] = (t0 + tk) * 2 + (tid & 1);
  }
}

// ---- fused FFN: r12 kernel verbatim + setprio around MFMA cluster (ONLY change) ----
// 64 tokens/block, 2 tok-groups/wave, single-barrier counted-vmcnt(8) pipeline.
// iter c: [lgkm;bar] stage{W1(c+1),W2(c)} vmcnt(8) setprio(1){GEMM1(c)||GEMM2(c-1)}setprio(0) h->hs
__global__ __launch_bounds__(256, 2) void moe_ffn(
    const unsigned short* __restrict__ xbf,
    const unsigned short* __restrict__ W1T,  // [E][H][D] bf16, swizzled
    const unsigned short* __restrict__ W2T,  // [E][H/32][D][32] bf16, chunk-tiled
    const float* __restrict__ b1g, const float* __restrict__ b2g,
    const int* __restrict__ counts, const int* __restrict__ list,
    unsigned short* __restrict__ ybuf) {
  int b = blockIdx.x;
  int e = b & 7;
  int r = b >> 3;
  int s = r & (NSLICE - 1);
  int t = r >> 2;
  int cnt = counts[e];
  if (t * MTILE >= cnt) return;

  __shared__ __align__(16) short W1b[2][HC * 256];   // 32 KB
  __shared__ __align__(16) short W2b[2][256 * HC];   // 32 KB
  __shared__ __align__(16) short hs[2][64][40];      // 10 KB

  int tid = threadIdx.x;
  int l = tid & 63, w = tid >> 6;
  int lr = l & 15, lg = l >> 4, kg = lg * 8;
  int wm = w & 1, wn = w >> 1;   // wm: 32-tok half; wn: hcol16 (GEMM1) / d-half128 (GEMM2)
  int hbase = s * HSLICE;
  const int* mylist = list + e * NTOK + t * MTILE;
  const unsigned short* W1e = W1T + (size_t)e * HID * DIM;
  const unsigned short* W2e = W2T + (size_t)e * HID * DIM;

  auto stage1 = [&](int hc, int buf) {   // W1 chunk: 16 KB linear, 4 loads/wave
    const char* src = (const char*)(W1e + (size_t)hc * DIM);
    char* dst = (char*)&W1b[buf][0];
    #pragma unroll
    for (int i = 0; i < 4; ++i) {
      int off = w * 4096 + i * 1024;
      __builtin_amdgcn_global_load_lds(
        (const __attribute__((address_space(1))) void*)(src + off + l * 16),
        (__attribute__((address_space(3))) void*)(dst + off), 16, 0, 0);
    }
  };
  auto stage2 = [&](int hc, int buf) {   // W2 chunk: 16 KB linear, 4 loads/wave
    const char* src = (const char*)(W2e + (size_t)(hc >> 5) * (DIM * 32));
    char* dst = (char*)&W2b[buf][0];
    #pragma unroll
    for (int i = 0; i < 4; ++i) {
      int off = w * 4096 + i * 1024;
      __builtin_amdgcn_global_load_lds(
        (const __attribute__((address_space(1))) void*)(src + off + l * 16),
        (__attribute__((address_space(3))) void*)(dst + off), 16, 0, 0);
    }
  };

  // ---- prologue: stage W1(0); b1 -> VGPRs (static idx); X frags (2 groups) -> VGPR ----
  stage1(hbase, 0);

  float bbreg[NCHUNK];
  #pragma unroll
  for (int c = 0; c < NCHUNK; ++c)
    bbreg[c] = b1g[e * HID + hbase + c * HC + wn * 16 + lr];

  float b2v[8];
  #pragma unroll
  for (int n = 0; n < 8; ++n)
    b2v[n] = (s == 0) ? b2g[e * DIM + wn * 128 + n * 16 + lr] : 0.f;

  s16x8 xa[2][8];
  #pragma unroll
  for (int mf = 0; mf < 2; ++mf) {
    int row = wm * 32 + mf * 16 + lr;
    int grow = t * MTILE + row;
    int entry = (grow < cnt) ? mylist[row] : mylist[0];
    const unsigned short* xsrc = xbf + (size_t)(entry >> 1) * DIM;
    #pragma unroll
    for (int kb = 0; kb < 8; ++kb)
      xa[mf][kb] = *(const s16x8*)(xsrc + kb * 32 + kg);
  }

  f32x4 acc[2][8] = {};
  #pragma unroll
  for (int mf = 0; mf < 2; ++mf) {
    #pragma unroll
    for (int n = 0; n < 8; ++n) initfence(acc[mf][n]);
  }

  __syncthreads();   // prologue drain once (stage1(0), bbreg, b2v, xa complete)

  int swz = (lr & 7) << 3;
  int brow = (wn * 16 + lr) << 8;   // W1b row base (256 elems/row)

  #pragma unroll
  for (int c = 0; c < NCHUNK; ++c) {
    int P = c & 1, Q = P ^ 1;

    // single all-wave sync per chunk; loads stay in flight across it
    asm volatile("s_waitcnt lgkmcnt(0)" ::: "memory");
    __builtin_amdgcn_s_barrier();
    __builtin_amdgcn_sched_barrier(0);

    // stage next: W1(c+1)->W1b[Q] (wraps harmlessly on last iter), W2(c)->W2b[P]
    stage1(hbase + (((c + 1) & (NCHUNK - 1)) * HC), Q);
    stage2(hbase + c * HC, P);

    // counted wait: previous iter's 8 loads must complete (never drains own)
    asm volatile("s_waitcnt vmcnt(8)" ::: "memory");
    __builtin_amdgcn_sched_barrier(0);

    __builtin_amdgcn_s_setprio(1);   // T5: favor MFMA-cluster waves

    // GEMM1(c): h(64x32) = X @ W1chunk^T; A regs (2 tok-groups), B LDS shared
    f32x4 h0[2] = {}, h1[2] = {};
    initfence(h0[0]); initfence(h0[1]); initfence(h1[0]); initfence(h1[1]);
    const short* w1p = &W1b[P][0];
    #pragma unroll
    for (int kb = 0; kb < 8; ++kb) {
      s16x8 bv = *(const s16x8*)&w1p[brow + ((kb * 32 + kg) ^ swz)];
      if (kb & 1) { mfma16(h1[0], xa[0][kb], bv); mfma16(h1[1], xa[1][kb], bv); }
      else        { mfma16(h0[0], xa[0][kb], bv); mfma16(h0[1], xa[1][kb], bv); }
    }

    // GEMM2(c-1): y += h(c-1) @ W2(c-1)^T — independent, interleaves with GEMM1
    if (c > 0) {
      s16x8 a0 = *(const s16x8*)&hs[Q][wm * 32 + lr][kg];
      s16x8 a1 = *(const s16x8*)&hs[Q][wm * 32 + 16 + lr][kg];
      const short* w2p = &W2b[Q][0];
      #pragma unroll
      for (int n = 0; n < 8; ++n) {
        int d = wn * 128 + n * 16 + lr;
        s16x8 bv = *(const s16x8*)&w2p[(d << 5) + ((lg ^ ((d >> 1) & 3)) << 3)];
        mfma16(acc[0][n], a0, bv);
        mfma16(acc[1][n], a1, bv);
      }
    }

    __builtin_amdgcn_s_setprio(0);

    // finish h(c): +b1, relu, write hs[P] for next iter
    accfence(h0[0]); accfence(h0[1]); accfence(h1[0]); accfence(h1[1]);
    float bb = bbreg[c];
    #pragma unroll
    for (int mf = 0; mf < 2; ++mf) {
      f32x4 h = h0[mf] + h1[mf];
      #pragma unroll
      for (int q = 0; q < 4; ++q)
        hs[P][wm * 32 + mf * 16 + lg * 4 + q][wn * 16 + lr] = (short)f2bf(fmaxf(h[q] + bb, 0.f));
    }
  }

  // ---- epilogue: GEMM2 for last chunk ----
  asm volatile("s_waitcnt vmcnt(0) lgkmcnt(0)" ::: "memory");
  __builtin_amdgcn_s_barrier();
  __builtin_amdgcn_sched_barrier(0);
  {
    const int Q = (NCHUNK - 1) & 1;   // = 1
    s16x8 a0 = *(const s16x8*)&hs[Q][wm * 32 + lr][kg];
    s16x8 a1 = *(const s16x8*)&hs[Q][wm * 32 + 16 + lr][kg];
    const short* w2p = &W2b[Q][0];
    #pragma unroll
    for (int n = 0; n < 8; ++n) {
      int d = wn * 128 + n * 16 + lr;
      s16x8 bv = *(const s16x8*)&w2p[(d << 5) + ((lg ^ ((d >> 1) & 3)) << 3)];
      mfma16(acc[0][n], a0, bv);
      mfma16(acc[1][n], a1, bv);
    }
  }

  // ---- epilogue: bf16 partial store to slot buffer (+b2 on slice 0) ----
  #pragma unroll
  for (int mf = 0; mf < 2; ++mf) {
    #pragma unroll
    for (int n = 0; n < 8; ++n) accfence(acc[mf][n]);
  }
  #pragma unroll
  for (int mf = 0; mf < 2; ++mf) {
    #pragma unroll
    for (int q = 0; q < 4; ++q) {
      int lrow = wm * 32 + mf * 16 + lg * 4 + q;
      int grow = t * MTILE + lrow;
      if (grow < cnt) {
        int entry = mylist[lrow];
        unsigned short* yrow = ybuf + ((size_t)entry * NSLICE + s) * DIM + wn * 128 + lr;
        #pragma unroll
        for (int n = 0; n < 8; ++n)
          yrow[n * 16] = f2bf(acc[mf][n][q] + b2v[n]);
      }
    }
  }
}

// ---- out[n][d] = sum of 8 slot-rows of bf16 ybuf ----
__global__ __launch_bounds__(256) void reduce8(const unsigned short* __restrict__ yb,
                                               float* __restrict__ out) {
  int i = (blockIdx.x * 256 + threadIdx.x) * 8;
  int n = i >> 8, d = i & 255;
  const unsigned short* base = yb + ((size_t)n * 8) * DIM + d;
  float sum[8] = {0,0,0,0,0,0,0,0};
  #pragma unroll
  for (int r = 0; r < 8; ++r) {
    s16x8 v = *(const s16x8*)(base + r * DIM);
    #pragma unroll
    for (int j = 0; j < 8; ++j) sum[j] += bf2f((unsigned short)v[j]);
  }
  float4 o0 = {sum[0], sum[1], sum[2], sum[3]};
  float4 o1 = {sum[4], sum[5], sum[6], sum[7]};
  *(float4*)(out + i) = o0;
  *(float4*)(out + i + 4) = o1;
}

extern "C" void kernel_launch(void* const* d_in, const int* in_sizes, int n_in,
                              void* d_out, int out_size, void* d_ws, size_t ws_size,
                              hipStream_t stream) {
  const float* x    = (const float*)d_in[0];
  const float* gW   = (const float*)d_in[1];
  const float* gb   = (const float*)d_in[2];
  const float* W1   = (const float*)d_in[3];
  const float* b1   = (const float*)d_in[4];
  const float* W2   = (const float*)d_in[5];
  const float* b2   = (const float*)d_in[6];
  const float* temp = (const float*)d_in[7];
  float* out = (float*)d_out;

  char* ws = (char*)d_ws;
  int*            counts = (int*)(ws + 0);                      // 256 B
  int*            list   = (int*)(ws + 256);                    // 128 KB
  unsigned short* xbf    = (unsigned short*)(ws + 131584);      // 2 MB
  unsigned short* W1T    = (unsigned short*)(ws + 2228736);     // 4 MB
  unsigned short* W2T    = (unsigned short*)(ws + 6423040);     // 4 MB
  unsigned short* ybuf   = (unsigned short*)(ws + 10617344);    // 16 MB bf16 (8 slots/token)

  hipMemsetAsync(counts, 0, 256, stream);
  prep_gate<<<4096 + NTOK/16, dim3(32, 8, 1), 0, stream>>>(
      W1, W2, W1T, W2T, x, gW, gb, temp, counts, list, xbf);
  moe_ffn<<<NEXP * (NTOK/MTILE) * NSLICE, 256, 0, stream>>>(xbf, W1T, W2T, b1, b2, counts, list, ybuf);
  reduce8<<<NTOK*DIM/2048, 256, 0, stream>>>(ybuf, out);
}

// Round 17
// 54.402 us; speedup vs baseline: 1.5133x; 1.0351x over previous
//
#include <hip/hip_runtime.h>
#include <hip/hip_bf16.h>
#include <stdint.h>

#define NTOK 4096
#define DIM  256
#define HID  1024
#define NEXP 8
#define MTILE 64
#define HC 32
#define HSLICE 256
#define NSLICE 4
#define NCHUNK (HSLICE / HC)   // 8

typedef float f32x4 __attribute__((ext_vector_type(4)));
typedef short s16x8 __attribute__((ext_vector_type(8)));

__device__ __forceinline__ unsigned short f2bf(float f) {
  union { float f; unsigned u; } v; v.f = f;
  unsigned r = v.u + 0x7FFFu + ((v.u >> 16) & 1u);
  return (unsigned short)(r >> 16);
}
__device__ __forceinline__ float bf2f(unsigned short s) {
  union { float f; unsigned u; } v; v.u = ((unsigned)s) << 16;
  return v.f;
}
__device__ __forceinline__ void mfma16(f32x4& acc, s16x8 a, s16x8 b) {
  asm("v_mfma_f32_16x16x32_bf16 %0, %1, %2, %0" : "+v"(acc) : "v"(a), "v"(b));
}
__device__ __forceinline__ void accfence(f32x4& a) {   // MFMA->VALU read hazard
  asm volatile("s_nop 7" : "+v"(a));
}
__device__ __forceinline__ void initfence(f32x4& a) {  // VALU init -> MFMA srcC hazard
  asm volatile("s_nop 1" : "+v"(a));
}

// ---- prep (coalesced 64x64 transpose + bf16 + swizzle) + gate/route ----
// blocks [0,512):   W1 [E][256][1024] f32 -> W1T [E][1024][256] bf16, col' = col ^ ((row&7)<<3)
// blocks [512,1024): W2 [E][1024][256] f32 -> W2T chunk-tiled [E][H/32][D][32] bf16,
//                    slot' = slot ^ ((d>>1)&3) within each 32-elem d-row
// blocks [1024,1280): gate+top2+routing, 16 tokens/block
// All weight stores are 16B-contiguous s16x8 (swizzles preserve 8-element runs).
__global__ __launch_bounds__(256) void prep_gate(
    const float* __restrict__ W1, const float* __restrict__ W2,
    unsigned short* __restrict__ W1T, unsigned short* __restrict__ W2T,
    const float* __restrict__ x, const float* __restrict__ gW,
    const float* __restrict__ gb, const float* __restrict__ temp,
    int* __restrict__ counts, int* __restrict__ list,
    unsigned short* __restrict__ xbf) {
  int id = blockIdx.x;
  int tid = threadIdx.x;

  if (id < 1024) {   // ---------- transpose jobs (64x64 f32 tiles) ----------
    __shared__ float tile[64][68];   // pad 68: b128-aligned rows, conflict-free col reads
    const float* in; int e, r0, c0, C, isW1;
    if (id < 512) {            // W1: 256x1024 in, 4 row-tiles x 16 col-tiles
      e = id >> 6; int rem = id & 63;
      r0 = (rem >> 4) * 64; c0 = (rem & 15) * 64;
      in = W1 + (size_t)e * 256 * 1024; C = 1024; isW1 = 1;
    } else {                   // W2: 1024x256 in, 16 row-tiles x 4 col-tiles
      int id2 = id - 512;
      e = id2 >> 6; int rem = id2 & 63;
      r0 = (rem >> 2) * 64; c0 = (rem & 3) * 64;
      in = W2 + (size_t)e * 1024 * 256; C = 256; isW1 = 0;
    }
    #pragma unroll
    for (int k = 0; k < 4; ++k) {
      int row = (tid >> 4) + k * 16;       // 0..63
      int col = (tid & 15) * 4;
      float4 v = *(const float4*)(in + (size_t)(r0 + row) * C + c0 + col);
      tile[row][col] = v.x; tile[row][col + 1] = v.y;
      tile[row][col + 2] = v.z; tile[row][col + 3] = v.w;
    }
    __syncthreads();
    #pragma unroll
    for (int k = 0; k < 2; ++k) {
      int orow = (tid >> 3) + k * 32;      // 0..63: output row (h for W1, d for W2)
      int i8 = (tid & 7) * 8;              // 0..56: output col 8-group
      unsigned short vals[8];
      #pragma unroll
      for (int j = 0; j < 8; ++j) vals[j] = f2bf(tile[i8 + j][orow]);
      if (isW1) {
        int h = c0 + orow;                 // W1 input col = h
        int d = r0 + i8;                   // W1 input row = d
        int sd = d ^ ((h & 7) << 3);       // flips bits 3..5 only; 8-run stays contiguous
        *(s16x8*)(W1T + ((size_t)e * HID + h) * DIM + sd) = *(s16x8*)vals;
      } else {
        int d = c0 + orow;                 // W2 input col = d
        int h = r0 + i8;                   // W2 input row = h (8-run within one 32-group)
        int ch = h >> 5, kk = h & 31;
        int slot = (kk >> 3) ^ ((d >> 1) & 3);
        *(s16x8*)(W2T + (size_t)e * HID * DIM + (size_t)ch * (DIM * 32) + d * 32 + slot * 8)
            = *(s16x8*)vals;
      }
    }
    return;
  }

  // ---------- gate job (16 tokens/block) ----------
  __shared__ int pairs[16][2];
  __shared__ int lcnt[NEXP], lbase[NEXP], lrank[NEXP];
  int w = tid >> 6, lane = tid & 63;
  int sl = lane & 15, g = lane >> 4;
  if (tid < NEXP) { lcnt[tid] = 0; lrank[tid] = 0; }
  __syncthreads();
  int t0 = (id - 1024) * 16;
  int tok = w * 4 + g;
  int n = t0 + tok;

  float4 xv[4];
  #pragma unroll
  for (int p = 0; p < 4; ++p)
    xv[p] = *reinterpret_cast<const float4*>(x + (size_t)n * DIM + sl * 16 + p * 4);
  {
    s16x8 xb0, xb1;
    xb0[0]=(short)f2bf(xv[0].x); xb0[1]=(short)f2bf(xv[0].y); xb0[2]=(short)f2bf(xv[0].z); xb0[3]=(short)f2bf(xv[0].w);
    xb0[4]=(short)f2bf(xv[1].x); xb0[5]=(short)f2bf(xv[1].y); xb0[6]=(short)f2bf(xv[1].z); xb0[7]=(short)f2bf(xv[1].w);
    xb1[0]=(short)f2bf(xv[2].x); xb1[1]=(short)f2bf(xv[2].y); xb1[2]=(short)f2bf(xv[2].z); xb1[3]=(short)f2bf(xv[2].w);
    xb1[4]=(short)f2bf(xv[3].x); xb1[5]=(short)f2bf(xv[3].y); xb1[6]=(short)f2bf(xv[3].z); xb1[7]=(short)f2bf(xv[3].w);
    *reinterpret_cast<s16x8*>(xbf + (size_t)n * DIM + sl * 16)     = xb0;
    *reinterpret_cast<s16x8*>(xbf + (size_t)n * DIM + sl * 16 + 8) = xb1;
  }
  float acc[NEXP];
  #pragma unroll
  for (int e = 0; e < NEXP; ++e) {
    const float* we = gW + (size_t)e * DIM + sl * 16;
    float a = 0.f;
    #pragma unroll
    for (int p = 0; p < 4; ++p) {
      float4 wv = *reinterpret_cast<const float4*>(we + p * 4);
      a += xv[p].x*wv.x + xv[p].y*wv.y + xv[p].z*wv.z + xv[p].w*wv.w;
    }
    acc[e] = a;
  }
  #pragma unroll
  for (int off = 1; off < 16; off <<= 1) {
    #pragma unroll
    for (int e = 0; e < NEXP; ++e) acc[e] += __shfl_xor(acc[e], off);
  }
  if (sl == 0) {
    float t = temp[0];
    float s[NEXP];
    #pragma unroll
    for (int e = 0; e < NEXP; ++e) s[e] = (acc[e] + gb[e]) / t;
    int b0 = 0; float v0 = s[0];
    #pragma unroll
    for (int e = 1; e < NEXP; ++e) if (s[e] > v0) { v0 = s[e]; b0 = e; }
    int b1i = 0; float v1 = -3.4e38f;
    #pragma unroll
    for (int e = 0; e < NEXP; ++e) if (e != b0 && s[e] > v1) { v1 = s[e]; b1i = e; }
    pairs[tok][0] = b0;
    pairs[tok][1] = b1i;
    atomicAdd(&lcnt[b0], 1);
    atomicAdd(&lcnt[b1i], 1);
  }
  __syncthreads();
  if (tid < NEXP) lbase[tid] = atomicAdd(&counts[tid], lcnt[tid]);
  __syncthreads();
  if (tid < 32) {
    int tk = tid >> 1;
    int e = pairs[tk][tid & 1];
    int r = atomicAdd(&lrank[e], 1);
    list[e * NTOK + lbase[e] + r] = (t0 + tk) * 2 + (tid & 1);
  }
}

// ---- fused FFN: r12 kernel verbatim (best measured config) ----
// 64 tokens/block, 2 tok-groups/wave, single-barrier counted-vmcnt(8) pipeline.
// iter c: [lgkm;bar] stage{W1(c+1),W2(c)} vmcnt(8) GEMM1(c)||GEMM2(c-1) h->hs[c&1]
__global__ __launch_bounds__(256, 2) void moe_ffn(
    const unsigned short* __restrict__ xbf,
    const unsigned short* __restrict__ W1T,  // [E][H][D] bf16, swizzled
    const unsigned short* __restrict__ W2T,  // [E][H/32][D][32] bf16, chunk-tiled
    const float* __restrict__ b1g, const float* __restrict__ b2g,
    const int* __restrict__ counts, const int* __restrict__ list,
    unsigned short* __restrict__ ybuf) {
  int b = blockIdx.x;
  int e = b & 7;
  int r = b >> 3;
  int s = r & (NSLICE - 1);
  int t = r >> 2;
  int cnt = counts[e];
  if (t * MTILE >= cnt) return;

  __shared__ __align__(16) short W1b[2][HC * 256];   // 32 KB
  __shared__ __align__(16) short W2b[2][256 * HC];   // 32 KB
  __shared__ __align__(16) short hs[2][64][40];      // 10 KB

  int tid = threadIdx.x;
  int l = tid & 63, w = tid >> 6;
  int lr = l & 15, lg = l >> 4, kg = lg * 8;
  int wm = w & 1, wn = w >> 1;   // wm: 32-tok half; wn: hcol16 (GEMM1) / d-half128 (GEMM2)
  int hbase = s * HSLICE;
  const int* mylist = list + e * NTOK + t * MTILE;
  const unsigned short* W1e = W1T + (size_t)e * HID * DIM;
  const unsigned short* W2e = W2T + (size_t)e * HID * DIM;

  auto stage1 = [&](int hc, int buf) {   // W1 chunk: 16 KB linear, 4 loads/wave
    const char* src = (const char*)(W1e + (size_t)hc * DIM);
    char* dst = (char*)&W1b[buf][0];
    #pragma unroll
    for (int i = 0; i < 4; ++i) {
      int off = w * 4096 + i * 1024;
      __builtin_amdgcn_global_load_lds(
        (const __attribute__((address_space(1))) void*)(src + off + l * 16),
        (__attribute__((address_space(3))) void*)(dst + off), 16, 0, 0);
    }
  };
  auto stage2 = [&](int hc, int buf) {   // W2 chunk: 16 KB linear, 4 loads/wave
    const char* src = (const char*)(W2e + (size_t)(hc >> 5) * (DIM * 32));
    char* dst = (char*)&W2b[buf][0];
    #pragma unroll
    for (int i = 0; i < 4; ++i) {
      int off = w * 4096 + i * 1024;
      __builtin_amdgcn_global_load_lds(
        (const __attribute__((address_space(1))) void*)(src + off + l * 16),
        (__attribute__((address_space(3))) void*)(dst + off), 16, 0, 0);
    }
  };

  // ---- prologue: stage W1(0); b1 -> VGPRs (static idx); X frags (2 groups) -> VGPR ----
  stage1(hbase, 0);

  float bbreg[NCHUNK];
  #pragma unroll
  for (int c = 0; c < NCHUNK; ++c)
    bbreg[c] = b1g[e * HID + hbase + c * HC + wn * 16 + lr];

  float b2v[8];
  #pragma unroll
  for (int n = 0; n < 8; ++n)
    b2v[n] = (s == 0) ? b2g[e * DIM + wn * 128 + n * 16 + lr] : 0.f;

  s16x8 xa[2][8];
  #pragma unroll
  for (int mf = 0; mf < 2; ++mf) {
    int row = wm * 32 + mf * 16 + lr;
    int grow = t * MTILE + row;
    int entry = (grow < cnt) ? mylist[row] : mylist[0];
    const unsigned short* xsrc = xbf + (size_t)(entry >> 1) * DIM;
    #pragma unroll
    for (int kb = 0; kb < 8; ++kb)
      xa[mf][kb] = *(const s16x8*)(xsrc + kb * 32 + kg);
  }

  f32x4 acc[2][8] = {};
  #pragma unroll
  for (int mf = 0; mf < 2; ++mf) {
    #pragma unroll
    for (int n = 0; n < 8; ++n) initfence(acc[mf][n]);
  }

  __syncthreads();   // prologue drain once (stage1(0), bbreg, b2v, xa complete)

  int swz = (lr & 7) << 3;
  int brow = (wn * 16 + lr) << 8;   // W1b row base (256 elems/row)

  #pragma unroll
  for (int c = 0; c < NCHUNK; ++c) {
    int P = c & 1, Q = P ^ 1;

    // single all-wave sync per chunk; loads stay in flight across it
    asm volatile("s_waitcnt lgkmcnt(0)" ::: "memory");
    __builtin_amdgcn_s_barrier();
    __builtin_amdgcn_sched_barrier(0);

    // stage next: W1(c+1)->W1b[Q] (wraps harmlessly on last iter), W2(c)->W2b[P]
    stage1(hbase + (((c + 1) & (NCHUNK - 1)) * HC), Q);
    stage2(hbase + c * HC, P);

    // counted wait: previous iter's 8 loads must complete (never drains own)
    asm volatile("s_waitcnt vmcnt(8)" ::: "memory");
    __builtin_amdgcn_sched_barrier(0);

    // GEMM1(c): h(64x32) = X @ W1chunk^T; A regs (2 tok-groups), B LDS shared
    f32x4 h0[2] = {}, h1[2] = {};
    initfence(h0[0]); initfence(h0[1]); initfence(h1[0]); initfence(h1[1]);
    const short* w1p = &W1b[P][0];
    #pragma unroll
    for (int kb = 0; kb < 8; ++kb) {
      s16x8 bv = *(const s16x8*)&w1p[brow + ((kb * 32 + kg) ^ swz)];
      if (kb & 1) { mfma16(h1[0], xa[0][kb], bv); mfma16(h1[1], xa[1][kb], bv); }
      else        { mfma16(h0[0], xa[0][kb], bv); mfma16(h0[1], xa[1][kb], bv); }
    }

    // GEMM2(c-1): y += h(c-1) @ W2(c-1)^T — independent, interleaves with GEMM1
    if (c > 0) {
      s16x8 a0 = *(const s16x8*)&hs[Q][wm * 32 + lr][kg];
      s16x8 a1 = *(const s16x8*)&hs[Q][wm * 32 + 16 + lr][kg];
      const short* w2p = &W2b[Q][0];
      #pragma unroll
      for (int n = 0; n < 8; ++n) {
        int d = wn * 128 + n * 16 + lr;
        s16x8 bv = *(const s16x8*)&w2p[(d << 5) + ((lg ^ ((d >> 1) & 3)) << 3)];
        mfma16(acc[0][n], a0, bv);
        mfma16(acc[1][n], a1, bv);
      }
    }

    // finish h(c): +b1, relu, write hs[P] for next iter
    accfence(h0[0]); accfence(h0[1]); accfence(h1[0]); accfence(h1[1]);
    float bb = bbreg[c];
    #pragma unroll
    for (int mf = 0; mf < 2; ++mf) {
      f32x4 h = h0[mf] + h1[mf];
      #pragma unroll
      for (int q = 0; q < 4; ++q)
        hs[P][wm * 32 + mf * 16 + lg * 4 + q][wn * 16 + lr] = (short)f2bf(fmaxf(h[q] + bb, 0.f));
    }
  }

  // ---- epilogue: GEMM2 for last chunk ----
  asm volatile("s_waitcnt vmcnt(0) lgkmcnt(0)" ::: "memory");
  __builtin_amdgcn_s_barrier();
  __builtin_amdgcn_sched_barrier(0);
  {
    const int Q = (NCHUNK - 1) & 1;   // = 1
    s16x8 a0 = *(const s16x8*)&hs[Q][wm * 32 + lr][kg];
    s16x8 a1 = *(const s16x8*)&hs[Q][wm * 32 + 16 + lr][kg];
    const short* w2p = &W2b[Q][0];
    #pragma unroll
    for (int n = 0; n < 8; ++n) {
      int d = wn * 128 + n * 16 + lr;
      s16x8 bv = *(const s16x8*)&w2p[(d << 5) + ((lg ^ ((d >> 1) & 3)) << 3)];
      mfma16(acc[0][n], a0, bv);
      mfma16(acc[1][n], a1, bv);
    }
  }

  // ---- epilogue: bf16 partial store to slot buffer (+b2 on slice 0) ----
  #pragma unroll
  for (int mf = 0; mf < 2; ++mf) {
    #pragma unroll
    for (int n = 0; n < 8; ++n) accfence(acc[mf][n]);
  }
  #pragma unroll
  for (int mf = 0; mf < 2; ++mf) {
    #pragma unroll
    for (int q = 0; q < 4; ++q) {
      int lrow = wm * 32 + mf * 16 + lg * 4 + q;
      int grow = t * MTILE + lrow;
      if (grow < cnt) {
        int entry = mylist[lrow];
        unsigned short* yrow = ybuf + ((size_t)entry * NSLICE + s) * DIM + wn * 128 + lr;
        #pragma unroll
        for (int n = 0; n < 8; ++n)
          yrow[n * 16] = f2bf(acc[mf][n][q] + b2v[n]);
      }
    }
  }
}

// ---- out[n][d] = sum of 8 slot-rows of bf16 ybuf ----
__global__ __launch_bounds__(256) void reduce8(const unsigned short* __restrict__ yb,
                                               float* __restrict__ out) {
  int i = (blockIdx.x * 256 + threadIdx.x) * 8;
  int n = i >> 8, d = i & 255;
  const unsigned short* base = yb + ((size_t)n * 8) * DIM + d;
  float sum[8] = {0,0,0,0,0,0,0,0};
  #pragma unroll
  for (int r = 0; r < 8; ++r) {
    s16x8 v = *(const s16x8*)(base + r * DIM);
    #pragma unroll
    for (int j = 0; j < 8; ++j) sum[j] += bf2f((unsigned short)v[j]);
  }
  float4 o0 = {sum[0], sum[1], sum[2], sum[3]};
  float4 o1 = {sum[4], sum[5], sum[6], sum[7]};
  *(float4*)(out + i) = o0;
  *(float4*)(out + i + 4) = o1;
}

extern "C" void kernel_launch(void* const* d_in, const int* in_sizes, int n_in,
                              void* d_out, int out_size, void* d_ws, size_t ws_size,
                              hipStream_t stream) {
  const float* x    = (const float*)d_in[0];
  const float* gW   = (const float*)d_in[1];
  const float* gb   = (const float*)d_in[2];
  const float* W1   = (const float*)d_in[3];
  const float* b1   = (const float*)d_in[4];
  const float* W2   = (const float*)d_in[5];
  const float* b2   = (const float*)d_in[6];
  const float* temp = (const float*)d_in[7];
  float* out = (float*)d_out;

  char* ws = (char*)d_ws;
  int*            counts = (int*)(ws + 0);                      // 256 B
  int*            list   = (int*)(ws + 256);                    // 128 KB
  unsigned short* xbf    = (unsigned short*)(ws + 131584);      // 2 MB
  unsigned short* W1T    = (unsigned short*)(ws + 2228736);     // 4 MB
  unsigned short* W2T    = (unsigned short*)(ws + 6423040);     // 4 MB
  unsigned short* ybuf   = (unsigned short*)(ws + 10617344);    // 16 MB bf16 (8 slots/token)

  hipMemsetAsync(counts, 0, 256, stream);
  prep_gate<<<1024 + NTOK/16, 256, 0, stream>>>(
      W1, W2, W1T, W2T, x, gW, gb, temp, counts, list, xbf);
  moe_ffn<<<NEXP * (NTOK/MTILE) * NSLICE, 256, 0, stream>>>(xbf, W1T, W2T, b1, b2, counts, list, ybuf);
  reduce8<<<NTOK*DIM/2048, 256, 0, stream>>>(ybuf, out);
}